// Round 2
// baseline (786.240 us; speedup 1.0000x reference)
//
#include <hip/hip_runtime.h>
#include <hip/hip_bf16.h>

#define D 256

// ------------------------------ CSR build ------------------------------

__global__ void hist_kernel(const int* __restrict__ src, int* __restrict__ cnt, int E) {
    int e = blockIdx.x * blockDim.x + threadIdx.x;
    if (e < E) atomicAdd(&cnt[src[e]], 1);
}

__global__ __launch_bounds__(256) void scan_kernel(const int* __restrict__ cnt,
        int* __restrict__ row_ptr, int* __restrict__ row_cur, int n) {
    __shared__ int part[256];
    int t = threadIdx.x;
    int chunk = (n + 255) / 256;
    int beg = t * chunk;
    int end = min(beg + chunk, n);
    int s = 0;
    for (int i = beg; i < end; ++i) s += cnt[i];
    part[t] = s;
    __syncthreads();
    for (int off = 1; off < 256; off <<= 1) {
        int v = (t >= off) ? part[t - off] : 0;
        __syncthreads();
        part[t] += v;
        __syncthreads();
    }
    int run = (t == 0) ? 0 : part[t - 1];
    for (int i = beg; i < end; ++i) {
        row_ptr[i] = run;
        row_cur[i] = run;
        run += cnt[i];
    }
    if (t == 255) row_ptr[n] = run;
}

__global__ void scatter_kernel(const int* __restrict__ src, const int* __restrict__ dst,
        const int* __restrict__ et, int* __restrict__ row_cur, int* __restrict__ eperm, int E) {
    int e = blockIdx.x * blockDim.x + threadIdx.x;
    if (e < E) {
        int pos = atomicAdd(&row_cur[src[e]], 1);
        eperm[pos] = dst[e] | (et[e] << 20);
    }
}

// ------------------------------ fp32 tiled GEMM ------------------------------
// C[m, colOff+n] = A[m,:] @ B[:,n] (+bias[n]) (optional relu)
// A: [M,K] row-major, B: [K,N] row-major, C row stride ldc.
// Block: 256 threads -> 64x64 tile, 4x4 per thread, K-step 16.

template <bool RELU>
__global__ __launch_bounds__(256) void gemm64(const float* __restrict__ A,
        const float* __restrict__ B, const float* __restrict__ bias,
        float* __restrict__ C, int M, int K, int N, int ldc, int colOff) {
    __shared__ float As[16][68];  // [k][m], padded so float4 rows stay 16B-aligned
    __shared__ float Bs[16][64];  // [k][n]

    const int tid = threadIdx.x;
    const int tx = tid & 15;
    const int ty = tid >> 4;
    const int m0 = blockIdx.x * 64;
    const int n0 = blockIdx.y * 64;

    const int arow  = tid >> 2;        // 0..63
    const int acolg = (tid & 3) * 4;   // 0,4,8,12
    const int brow  = tid >> 4;        // 0..15
    const int bcol  = (tid & 15) * 4;  // 0..60

    const bool avalid = (m0 + arow) < M;

    float acc[4][4];
#pragma unroll
    for (int i = 0; i < 4; ++i)
#pragma unroll
        for (int j = 0; j < 4; ++j) acc[i][j] = 0.0f;

    for (int kk = 0; kk < K; kk += 16) {
        float4 a4 = make_float4(0.f, 0.f, 0.f, 0.f);
        if (avalid) a4 = *reinterpret_cast<const float4*>(A + (size_t)(m0 + arow) * K + kk + acolg);
        float4 b4 = *reinterpret_cast<const float4*>(B + (size_t)(kk + brow) * N + n0 + bcol);

        As[acolg + 0][arow] = a4.x;
        As[acolg + 1][arow] = a4.y;
        As[acolg + 2][arow] = a4.z;
        As[acolg + 3][arow] = a4.w;
        *reinterpret_cast<float4*>(&Bs[brow][bcol]) = b4;
        __syncthreads();

#pragma unroll
        for (int k = 0; k < 16; ++k) {
            float4 av = *reinterpret_cast<const float4*>(&As[k][ty * 4]);
            float4 bv = *reinterpret_cast<const float4*>(&Bs[k][tx * 4]);
            const float a[4] = {av.x, av.y, av.z, av.w};
            const float b[4] = {bv.x, bv.y, bv.z, bv.w};
#pragma unroll
            for (int i = 0; i < 4; ++i)
#pragma unroll
                for (int j = 0; j < 4; ++j) acc[i][j] = fmaf(a[i], b[j], acc[i][j]);
        }
        __syncthreads();
    }

#pragma unroll
    for (int i = 0; i < 4; ++i) {
        int m = m0 + ty * 4 + i;
        if (m >= M) continue;
#pragma unroll
        for (int j = 0; j < 4; ++j) {
            int n = n0 + tx * 4 + j;
            float v = acc[i][j];
            if (bias) v += bias[n];
            if (RELU) v = fmaxf(v, 0.0f);
            C[(size_t)m * ldc + colOff + n] = v;
        }
    }
}

// ------------------------------ edge aggregation ------------------------------
// io holds h@R+b (written by the root GEMM); this kernel overwrites it with
// relu(mean_{edges of type rel}(hr[dst]) + io). One wave (64 lanes) per node.

__global__ __launch_bounds__(256) void aggregate_kernel(const float* __restrict__ hr,
        const int* __restrict__ row_ptr, const int* __restrict__ eperm,
        float* __restrict__ io, int ldo, int coff, int rel, int N) {
    int node = blockIdx.x * 4 + (threadIdx.x >> 6);
    int lane = threadIdx.x & 63;
    if (node >= N) return;

    int beg = row_ptr[node];
    int end = row_ptr[node + 1];
    float4 acc = make_float4(0.f, 0.f, 0.f, 0.f);
    int cnt = 0;
    for (int e = beg; e < end; ++e) {
        int p = eperm[e];
        if ((p >> 20) == rel) {
            const float4 v = *reinterpret_cast<const float4*>(hr + (size_t)(p & 0xFFFFF) * D + lane * 4);
            acc.x += v.x; acc.y += v.y; acc.z += v.z; acc.w += v.w;
            ++cnt;
        }
    }
    float inv = 1.0f / fmaxf((float)cnt, 1.0f);
    float* o = io + (size_t)node * ldo + coff + lane * 4;
    float4 r = *reinterpret_cast<const float4*>(o);
    float4 res;
    res.x = fmaxf(fmaf(acc.x, inv, r.x), 0.0f);
    res.y = fmaxf(fmaf(acc.y, inv, r.y), 0.0f);
    res.z = fmaxf(fmaf(acc.z, inv, r.z), 0.0f);
    res.w = fmaxf(fmaf(acc.w, inv, r.w), 0.0f);
    *reinterpret_cast<float4*>(o) = res;
}

// ------------------------------ fc2 + log_softmax head ------------------------------
// One wave per node: 256-dim dot against 16 columns, butterfly reduce, log_softmax.

__global__ __launch_bounds__(256) void head_kernel(const float* __restrict__ hid,
        const float* __restrict__ w2, const float* __restrict__ b2,
        float* __restrict__ out, int N) {
    int node = blockIdx.x * 4 + (threadIdx.x >> 6);
    int lane = threadIdx.x & 63;
    if (node >= N) return;

    float4 h4 = *reinterpret_cast<const float4*>(hid + (size_t)node * D + lane * 4);
    const float hv[4] = {h4.x, h4.y, h4.z, h4.w};

    float acc[16];
#pragma unroll
    for (int o = 0; o < 16; ++o) acc[o] = 0.0f;
#pragma unroll
    for (int j = 0; j < 4; ++j) {
        int k = lane * 4 + j;
        const float4 w0 = *reinterpret_cast<const float4*>(w2 + (size_t)k * 16 + 0);
        const float4 w1 = *reinterpret_cast<const float4*>(w2 + (size_t)k * 16 + 4);
        const float4 w2v = *reinterpret_cast<const float4*>(w2 + (size_t)k * 16 + 8);
        const float4 w3 = *reinterpret_cast<const float4*>(w2 + (size_t)k * 16 + 12);
        acc[0] = fmaf(hv[j], w0.x, acc[0]);  acc[1] = fmaf(hv[j], w0.y, acc[1]);
        acc[2] = fmaf(hv[j], w0.z, acc[2]);  acc[3] = fmaf(hv[j], w0.w, acc[3]);
        acc[4] = fmaf(hv[j], w1.x, acc[4]);  acc[5] = fmaf(hv[j], w1.y, acc[5]);
        acc[6] = fmaf(hv[j], w1.z, acc[6]);  acc[7] = fmaf(hv[j], w1.w, acc[7]);
        acc[8] = fmaf(hv[j], w2v.x, acc[8]); acc[9] = fmaf(hv[j], w2v.y, acc[9]);
        acc[10] = fmaf(hv[j], w2v.z, acc[10]); acc[11] = fmaf(hv[j], w2v.w, acc[11]);
        acc[12] = fmaf(hv[j], w3.x, acc[12]); acc[13] = fmaf(hv[j], w3.y, acc[13]);
        acc[14] = fmaf(hv[j], w3.z, acc[14]); acc[15] = fmaf(hv[j], w3.w, acc[15]);
    }
#pragma unroll
    for (int o = 0; o < 16; ++o) {
        float v = acc[o];
#pragma unroll
        for (int s = 32; s >= 1; s >>= 1) v += __shfl_xor(v, s);
        acc[o] = v + b2[o];
    }
    float mx = acc[0];
#pragma unroll
    for (int o = 1; o < 16; ++o) mx = fmaxf(mx, acc[o]);
    float se = 0.0f;
#pragma unroll
    for (int o = 0; o < 16; ++o) se += expf(acc[o] - mx);
    float lse = mx + logf(se);
    if (lane < 16) out[(size_t)node * 16 + lane] = acc[lane] - lse;
}

// ------------------------------ launch ------------------------------

extern "C" void kernel_launch(void* const* d_in, const int* in_sizes, int n_in,
                              void* d_out, int out_size, void* d_ws, size_t ws_size,
                              hipStream_t stream) {
    const float* x      = (const float*)d_in[0];
    const int*   ei     = (const int*)d_in[1];
    const int*   et     = (const int*)d_in[2];
    const float* rel_W  = (const float*)d_in[3];
    const float* root_W = (const float*)d_in[4];
    const float* bias   = (const float*)d_in[5];
    const float* fc1_w  = (const float*)d_in[6];
    const float* fc1_b  = (const float*)d_in[7];
    const float* fc2_w  = (const float*)d_in[8];
    const float* fc2_b  = (const float*)d_in[9];
    float* out = (float*)d_out;

    const int N = in_sizes[0] / D;  // 20000
    const int E = in_sizes[2];      // 500000
    const int* src = ei;
    const int* dst = ei + E;

    float* h1   = (float*)d_ws;                    // N*D
    float* hr   = h1 + (size_t)N * D;              // N*D
    float* hcat = hr + (size_t)N * D;              // N*2D
    float* hid  = h1;                              // reuse after convs
    int* row_ptr = (int*)(hcat + (size_t)N * 2 * D);
    int* row_cur = row_ptr + (N + 1);
    int* cnt_i   = row_cur + N;
    int* eperm   = cnt_i + N;

    // CSR by src, packed (dst | type<<20)
    hipMemsetAsync(cnt_i, 0, N * sizeof(int), stream);
    hist_kernel<<<dim3((E + 255) / 256), dim3(256), 0, stream>>>(src, cnt_i, E);
    scan_kernel<<<dim3(1), dim3(256), 0, stream>>>(cnt_i, row_ptr, row_cur, N);
    scatter_kernel<<<dim3((E + 255) / 256), dim3(256), 0, stream>>>(src, dst, et, row_cur, eperm, E);

    dim3 ggrid((N + 63) / 64, D / 64);
    dim3 gblock(256);
    dim3 ngrid((N + 3) / 4);

    static const int rels[4] = {0, 1, 2, 3};  // flattened METAPATHS
    for (int mp = 0; mp < 2; ++mp) {
        const float* hin = x;
        for (int hop = 0; hop < 2; ++hop) {
            int ci = mp * 2 + hop;
            int rel = rels[ci];
            const float* W = rel_W + ((size_t)ci * 5 + rel) * D * D;
            const float* R = root_W + (size_t)ci * D * D;
            const float* b = bias + (size_t)ci * D;
            float* outp; int ldo, coff;
            if (hop == 0) { outp = h1; ldo = D; coff = 0; }
            else          { outp = hcat; ldo = 2 * D; coff = mp * D; }
            // hr = hin @ W
            gemm64<false><<<ggrid, gblock, 0, stream>>>(hin, W, nullptr, hr, N, D, D, D, 0);
            // outp = hin @ R + b   (root term, pre-relu)
            gemm64<false><<<ggrid, gblock, 0, stream>>>(hin, R, b, outp, N, D, D, ldo, coff);
            // outp = relu(mean_agg(hr) + outp)
            aggregate_kernel<<<ngrid, gblock, 0, stream>>>(hr, row_ptr, eperm, outp, ldo, coff, rel, N);
            hin = h1;
        }
    }
    // hid = relu(hcat @ fc1_w + fc1_b)
    gemm64<true><<<ggrid, gblock, 0, stream>>>(hcat, fc1_w, fc1_b, hid, N, 2 * D, D, D, 0);
    // out = log_softmax(hid @ fc2_w + fc2_b)
    head_kernel<<<ngrid, gblock, 0, stream>>>(hid, fc2_w, fc2_b, out, N);
}

// Round 3
// 519.317 us; speedup vs baseline: 1.5140x; 1.5140x over previous
//
#include <hip/hip_runtime.h>
#include <hip/hip_bf16.h>

#define D 256
typedef unsigned short u16;
typedef __attribute__((ext_vector_type(8))) short bf16x8;
typedef __attribute__((ext_vector_type(4))) float f32x4;

__device__ inline u16 f2bf(float f) {
    unsigned u = __builtin_bit_cast(unsigned, f);
    unsigned r = (u + 0x7fff + ((u >> 16) & 1)) >> 16;   // RNE
    return (u16)r;
}
__device__ inline float bf2f(u16 u) {
    return __builtin_bit_cast(float, (unsigned)u << 16);
}

// ------------------------------ per-relation CSR build ------------------------------
// key = rel*N + src for rel in [0,4); rel 4 edges dropped (never aggregated).

__global__ void hist_kernel(const int* __restrict__ src, const int* __restrict__ et,
                            int* __restrict__ cnt, int E, int N) {
    int e = blockIdx.x * blockDim.x + threadIdx.x;
    if (e < E) {
        int r = et[e];
        if (r < 4) atomicAdd(&cnt[r * N + src[e]], 1);
    }
}

__global__ __launch_bounds__(256) void scan_kernel(const int* __restrict__ cnt,
        int* __restrict__ row_ptr, int* __restrict__ row_cur, int n) {
    __shared__ int part[256];
    int t = threadIdx.x;
    int chunk = (n + 255) / 256;
    int beg = t * chunk;
    int end = min(beg + chunk, n);
    int s = 0;
    for (int i = beg; i < end; ++i) s += cnt[i];
    part[t] = s;
    __syncthreads();
    for (int off = 1; off < 256; off <<= 1) {
        int v = (t >= off) ? part[t - off] : 0;
        __syncthreads();
        part[t] += v;
        __syncthreads();
    }
    int run = (t == 0) ? 0 : part[t - 1];
    for (int i = beg; i < end; ++i) {
        row_ptr[i] = run;
        row_cur[i] = run;
        run += cnt[i];
    }
    if (t == 255) row_ptr[n] = run;
}

__global__ void scatter_kernel(const int* __restrict__ src, const int* __restrict__ dst,
        const int* __restrict__ et, int* __restrict__ row_cur, int* __restrict__ eperm,
        int E, int N) {
    int e = blockIdx.x * blockDim.x + threadIdx.x;
    if (e < E) {
        int r = et[e];
        if (r < 4) {
            int pos = atomicAdd(&row_cur[r * N + src[e]], 1);
            eperm[pos] = dst[e];
        }
    }
}

// ------------------------------ casts / weight prep ------------------------------

__global__ void cast_x_kernel(const float* __restrict__ x, u16* __restrict__ xb, int n4) {
    int i = blockIdx.x * blockDim.x + threadIdx.x;
    if (i < n4) {
        float4 v = reinterpret_cast<const float4*>(x)[i];
        ushort4 o;
        o.x = f2bf(v.x); o.y = f2bf(v.y); o.z = f2bf(v.z); o.w = f2bf(v.w);
        reinterpret_cast<ushort4*>(xb)[i] = o;
    }
}

// Wcat[ci][n][k] bf16 (n<256 -> rel_W[ci][ci][k][n] ; n>=256 -> root_W[ci][k][n-256])
__global__ void build_wt_kernel(const float* __restrict__ rel_W,
                                const float* __restrict__ root_W, u16* __restrict__ Wcat) {
    int t = blockIdx.x * blockDim.x + threadIdx.x;   // 4*512*256 total
    int k = t & 255;
    int n = (t >> 8) & 511;
    int ci = t >> 17;
    float v;
    if (n < 256) v = rel_W[(((size_t)ci * 5 + ci) * 256 + k) * 256 + n];
    else         v = root_W[((size_t)ci * 256 + k) * 256 + (n - 256)];
    Wcat[t] = f2bf(v);
}

// fc1t[n][k] = fc1_w[k][n], bf16. n<256, k<512.
__global__ void build_fc1t_kernel(const float* __restrict__ fc1_w, u16* __restrict__ fc1t) {
    int t = blockIdx.x * blockDim.x + threadIdx.x;   // 256*512 total
    int k = t & 511;
    int n = t >> 9;
    fc1t[t] = f2bf(fc1_w[(size_t)k * 256 + n]);
}

// ------------------------------ bf16 MFMA GEMM ------------------------------
// A [M,K] bf16 row-major; Bt [NN,K] bf16 row-major (pre-transposed weights).
// Tile: BM=64 (4 waves x 16 rows), BN=128, BK=64. B staged in LDS with 3-bit XOR
// swizzle (source-side pre-swizzle for global_load_lds + swizzled ds_read).
// MODE 0 (conv): gn<256 -> out_bf=hr (bf16, no bias); gn>=256 -> out_f=root (fp32 +bias)
// MODE 1 (fc1):  out_bf = relu(acc + bias) bf16, row stride ldo_bf.

#define BM 64
#define BN 128
#define BK 64

template <int MODE>
__global__ __launch_bounds__(256) void gemm_mfma(
        const u16* __restrict__ A, const u16* __restrict__ Bt, int M, int K,
        u16* __restrict__ out_bf, float* __restrict__ out_f,
        const float* __restrict__ bias, int ldo_bf) {
    __shared__ u16 Bs[BN * BK];   // 16 KB, physically swizzled

    const int tid  = threadIdx.x;
    const int wave = tid >> 6, lane = tid & 63;
    const int l15 = lane & 15, lg = lane >> 4;
    const int m0 = blockIdx.x * BM + wave * 16;
    const int n0 = blockIdx.y * BN;

    f32x4 acc[8];
#pragma unroll
    for (int j = 0; j < 8; ++j) acc[j] = (f32x4){0.f, 0.f, 0.f, 0.f};

    const int  arow = m0 + l15;
    const bool aval = arow < M;
    const u16* Arow = A + (size_t)arow * K;

    for (int k0 = 0; k0 < K; k0 += BK) {
        __syncthreads();
        // stage B tile: 16 KB = 4 issues x 256 lanes x 16 B. LDS dest linear
        // (tid*16); source global address carries the inverse swizzle.
#pragma unroll
        for (int i = 0; i < 4; ++i) {
            int phys = i * 4096 + tid * 16;
            int n    = phys >> 7;                       // row within tile (128 B rows)
            int cl   = (phys & 127) ^ ((n & 7) << 4);   // logical byte within row
            const u16* srcp = Bt + (size_t)(n0 + n) * K + k0 + (cl >> 1);
            __builtin_amdgcn_global_load_lds(
                (const __attribute__((address_space(1))) void*)srcp,
                (__attribute__((address_space(3))) void*)((char*)Bs + phys), 16, 0, 0);
        }
        bf16x8 afr[2];
        if (aval) {
            afr[0] = *reinterpret_cast<const bf16x8*>(Arow + k0 + lg * 8);
            afr[1] = *reinterpret_cast<const bf16x8*>(Arow + k0 + 32 + lg * 8);
        } else {
            afr[0] = afr[1] = (bf16x8){0, 0, 0, 0, 0, 0, 0, 0};
        }
        __syncthreads();   // drains vmcnt(0) -> staged tile + A frags ready
#pragma unroll
        for (int kk = 0; kk < 2; ++kk) {
#pragma unroll
            for (int j = 0; j < 8; ++j) {
                int n    = j * 16 + l15;
                int cl   = kk * 64 + lg * 16;
                int phys = n * 128 + (cl ^ ((n & 7) << 4));
                bf16x8 bfr = *reinterpret_cast<const bf16x8*>((const char*)Bs + phys);
                acc[j] = __builtin_amdgcn_mfma_f32_16x16x32_bf16(afr[kk], bfr, acc[j], 0, 0, 0);
            }
        }
    }

    // epilogue: D col = lane&15, row = (lane>>4)*4 + reg  [m89/m91 verified]
    const int orow = m0 + lg * 4;
#pragma unroll
    for (int j = 0; j < 8; ++j) {
        int gn = n0 + j * 16 + l15;
#pragma unroll
        for (int r = 0; r < 4; ++r) {
            int m = orow + r;
            if (m >= M) continue;
            float v = acc[j][r];
            if (MODE == 0) {
                if (gn < 256) out_bf[(size_t)m * 256 + gn] = f2bf(v);
                else          out_f[(size_t)m * 256 + gn - 256] = v + bias[gn - 256];
            } else {
                v = fmaxf(v + bias[gn], 0.0f);
                out_bf[(size_t)m * ldo_bf + gn] = f2bf(v);
            }
        }
    }
}

// ------------------------------ edge aggregation (bf16) ------------------------------
// dst[node, coff + :] = relu(mean_{edges}(hr[dst_node]) + root[node]) as bf16.
// One wave per node; row_ptr pre-offset by ci*N (per-rel CSR).

__global__ __launch_bounds__(256) void aggregate_kernel(const u16* __restrict__ hr,
        const int* __restrict__ row_ptr, const int* __restrict__ eperm,
        const float* __restrict__ root, u16* __restrict__ dst,
        int ldo, int coff, int N) {
    int node = blockIdx.x * 4 + (threadIdx.x >> 6);
    int lane = threadIdx.x & 63;
    if (node >= N) return;

    int beg = row_ptr[node];
    int end = row_ptr[node + 1];
    float a0 = 0.f, a1 = 0.f, a2 = 0.f, a3 = 0.f;
    for (int e = beg; e < end; ++e) {
        int d = eperm[e];
        ushort4 v = *reinterpret_cast<const ushort4*>(hr + (size_t)d * 256 + lane * 4);
        a0 += bf2f(v.x); a1 += bf2f(v.y); a2 += bf2f(v.z); a3 += bf2f(v.w);
    }
    float inv = 1.0f / fmaxf((float)(end - beg), 1.0f);
    float4 r = *reinterpret_cast<const float4*>(root + (size_t)node * 256 + lane * 4);
    ushort4 o;
    o.x = f2bf(fmaxf(fmaf(a0, inv, r.x), 0.0f));
    o.y = f2bf(fmaxf(fmaf(a1, inv, r.y), 0.0f));
    o.z = f2bf(fmaxf(fmaf(a2, inv, r.z), 0.0f));
    o.w = f2bf(fmaxf(fmaf(a3, inv, r.w), 0.0f));
    *reinterpret_cast<ushort4*>(dst + (size_t)node * ldo + coff + lane * 4) = o;
}

// ------------------------------ fc2 + log_softmax head ------------------------------

__global__ __launch_bounds__(256) void head_kernel(const u16* __restrict__ hid,
        const float* __restrict__ w2, const float* __restrict__ b2,
        float* __restrict__ out, int N) {
    int node = blockIdx.x * 4 + (threadIdx.x >> 6);
    int lane = threadIdx.x & 63;
    if (node >= N) return;

    ushort4 h4 = *reinterpret_cast<const ushort4*>(hid + (size_t)node * 256 + lane * 4);
    const float hv[4] = {bf2f(h4.x), bf2f(h4.y), bf2f(h4.z), bf2f(h4.w)};

    float acc[16];
#pragma unroll
    for (int o = 0; o < 16; ++o) acc[o] = 0.0f;
#pragma unroll
    for (int j = 0; j < 4; ++j) {
        int k = lane * 4 + j;
        const float4 w0 = *reinterpret_cast<const float4*>(w2 + (size_t)k * 16 + 0);
        const float4 w1 = *reinterpret_cast<const float4*>(w2 + (size_t)k * 16 + 4);
        const float4 w2v = *reinterpret_cast<const float4*>(w2 + (size_t)k * 16 + 8);
        const float4 w3 = *reinterpret_cast<const float4*>(w2 + (size_t)k * 16 + 12);
        acc[0] = fmaf(hv[j], w0.x, acc[0]);   acc[1] = fmaf(hv[j], w0.y, acc[1]);
        acc[2] = fmaf(hv[j], w0.z, acc[2]);   acc[3] = fmaf(hv[j], w0.w, acc[3]);
        acc[4] = fmaf(hv[j], w1.x, acc[4]);   acc[5] = fmaf(hv[j], w1.y, acc[5]);
        acc[6] = fmaf(hv[j], w1.z, acc[6]);   acc[7] = fmaf(hv[j], w1.w, acc[7]);
        acc[8] = fmaf(hv[j], w2v.x, acc[8]);  acc[9] = fmaf(hv[j], w2v.y, acc[9]);
        acc[10] = fmaf(hv[j], w2v.z, acc[10]); acc[11] = fmaf(hv[j], w2v.w, acc[11]);
        acc[12] = fmaf(hv[j], w3.x, acc[12]); acc[13] = fmaf(hv[j], w3.y, acc[13]);
        acc[14] = fmaf(hv[j], w3.z, acc[14]); acc[15] = fmaf(hv[j], w3.w, acc[15]);
    }
#pragma unroll
    for (int o = 0; o < 16; ++o) {
        float v = acc[o];
#pragma unroll
        for (int s = 32; s >= 1; s >>= 1) v += __shfl_xor(v, s);
        acc[o] = v + b2[o];
    }
    float mx = acc[0];
#pragma unroll
    for (int o = 1; o < 16; ++o) mx = fmaxf(mx, acc[o]);
    float se = 0.0f;
#pragma unroll
    for (int o = 0; o < 16; ++o) se += expf(acc[o] - mx);
    float lse = mx + logf(se);
    if (lane < 16) out[(size_t)node * 16 + lane] = acc[lane] - lse;
}

// ------------------------------ launch ------------------------------

extern "C" void kernel_launch(void* const* d_in, const int* in_sizes, int n_in,
                              void* d_out, int out_size, void* d_ws, size_t ws_size,
                              hipStream_t stream) {
    const float* x      = (const float*)d_in[0];
    const int*   ei     = (const int*)d_in[1];
    const int*   et     = (const int*)d_in[2];
    const float* rel_W  = (const float*)d_in[3];
    const float* root_W = (const float*)d_in[4];
    const float* bias   = (const float*)d_in[5];
    const float* fc1_w  = (const float*)d_in[6];
    const float* fc1_b  = (const float*)d_in[7];
    const float* fc2_w  = (const float*)d_in[8];
    const float* fc2_b  = (const float*)d_in[9];
    float* out = (float*)d_out;

    const int N = in_sizes[0] / D;   // 20000
    const int E = in_sizes[2];       // 500000
    const int* src = ei;
    const int* dst = ei + E;

    char* w = (char*)d_ws;
    u16* xb    = (u16*)w;  w += (size_t)N * 256 * 2;
    u16* h1b   = (u16*)w;  w += (size_t)N * 256 * 2;
    u16* hcatb = (u16*)w;  w += (size_t)N * 512 * 2;
    u16* hr    = (u16*)w;  w += (size_t)N * 256 * 2;
    float* root = (float*)w; w += (size_t)N * 256 * 4;
    u16* Wcat  = (u16*)w;  w += (size_t)4 * 512 * 256 * 2;
    u16* fc1t  = (u16*)w;  w += (size_t)256 * 512 * 2;
    int* cnt     = (int*)w;  w += (size_t)4 * N * 4;
    int* row_ptr = (int*)w;  w += ((size_t)4 * N + 1) * 4;
    int* row_cur = (int*)w;  w += (size_t)4 * N * 4;
    int* eperm   = (int*)w;  w += (size_t)E * 4;
    u16* hid = h1b;   // reuse after convs

    // per-relation CSR
    hipMemsetAsync(cnt, 0, (size_t)4 * N * 4, stream);
    hist_kernel<<<dim3((E + 255) / 256), dim3(256), 0, stream>>>(src, et, cnt, E, N);
    scan_kernel<<<dim3(1), dim3(256), 0, stream>>>(cnt, row_ptr, row_cur, 4 * N);
    scatter_kernel<<<dim3((E + 255) / 256), dim3(256), 0, stream>>>(src, dst, et, row_cur, eperm, E, N);

    // precision prep
    cast_x_kernel<<<dim3((N * 256 / 4 + 255) / 256), dim3(256), 0, stream>>>(x, xb, N * 256 / 4);
    build_wt_kernel<<<dim3(4 * 512 * 256 / 256), dim3(256), 0, stream>>>(rel_W, root_W, Wcat);
    build_fc1t_kernel<<<dim3(256 * 512 / 256), dim3(256), 0, stream>>>(fc1_w, fc1t);

    dim3 gblock(256);
    dim3 ngrid((N + 3) / 4);
    dim3 cgrid((N + BM - 1) / BM, 512 / BN);   // conv fused NN=512
    dim3 fgrid((N + BM - 1) / BM, 256 / BN);   // fc1 NN=256

    for (int ci = 0; ci < 4; ++ci) {
        int mp = ci >> 1, hop = ci & 1;
        const u16* hin = (hop == 0) ? xb : h1b;
        gemm_mfma<0><<<cgrid, gblock, 0, stream>>>(hin, Wcat + (size_t)ci * 512 * 256,
                N, 256, hr, root, bias + (size_t)ci * 256, 256);
        u16* dstb; int ldo, coff;
        if (hop == 0) { dstb = h1b;   ldo = 256; coff = 0; }
        else          { dstb = hcatb; ldo = 512; coff = mp * 256; }
        aggregate_kernel<<<ngrid, gblock, 0, stream>>>(hr, row_ptr + (size_t)ci * N, eperm,
                root, dstb, ldo, coff, N);
    }
    // hid = relu(hcat @ fc1 + b)
    gemm_mfma<1><<<fgrid, gblock, 0, stream>>>(hcatb, fc1t, N, 512, hid, nullptr, fc1_b, 256);
    // out = log_softmax(hid @ fc2 + b)
    head_kernel<<<ngrid, gblock, 0, stream>>>(hid, fc2_w, fc2_b, out, N);
}

// Round 6
// 352.438 us; speedup vs baseline: 2.2309x; 1.4735x over previous
//
#include <hip/hip_runtime.h>
#include <hip/hip_bf16.h>

#define D 256
typedef unsigned short u16;
typedef __attribute__((ext_vector_type(8))) short bf16x8;
typedef __attribute__((ext_vector_type(4))) float f32x4;

__device__ inline u16 f2bf(float f) {
    unsigned u = __builtin_bit_cast(unsigned, f);
    unsigned r = (u + 0x7fff + ((u >> 16) & 1)) >> 16;   // RNE
    return (u16)r;
}
__device__ inline float bf2f(u16 u) {
    return __builtin_bit_cast(float, (unsigned)u << 16);
}

// ------------------------------ per-relation CSR build ------------------------------
// key = rel*N + src for rel in [0,4); rel 4 edges dropped (never aggregated).

__global__ void hist_kernel(const int* __restrict__ src, const int* __restrict__ et,
                            int* __restrict__ cnt, int E, int N) {
    int e = blockIdx.x * blockDim.x + threadIdx.x;
    if (e < E) {
        int r = et[e];
        if (r < 4) atomicAdd(&cnt[r * N + src[e]], 1);
    }
}

// ---- 3-phase device scan (replaces the 188us single-block scan) ----
#define SCAN_BLK 4096

__global__ __launch_bounds__(256) void scan_reduce_kernel(const int* __restrict__ cnt,
        int* __restrict__ bsum, int n) {
    __shared__ int s[256];
    int base = blockIdx.x * SCAN_BLK;
    int t = threadIdx.x;
    int sum = 0;
    for (int i = t; i < SCAN_BLK; i += 256) {
        int idx = base + i;
        if (idx < n) sum += cnt[idx];
    }
    s[t] = sum;
    __syncthreads();
    for (int off = 128; off > 0; off >>= 1) {
        if (t < off) s[t] += s[t + off];
        __syncthreads();
    }
    if (t == 0) bsum[blockIdx.x] = s[0];
}

__global__ __launch_bounds__(256) void scan_sums_kernel(const int* __restrict__ bsum,
        int* __restrict__ boff, int nb, int* __restrict__ row_ptr, int n) {
    __shared__ int s[256];
    int t = threadIdx.x;
    s[t] = (t < nb) ? bsum[t] : 0;
    __syncthreads();
    for (int off = 1; off < 256; off <<= 1) {
        int v = (t >= off) ? s[t - off] : 0;
        __syncthreads();
        s[t] += v;
        __syncthreads();
    }
    if (t < nb) boff[t] = (t == 0) ? 0 : s[t - 1];
    if (t == 255) row_ptr[n] = s[255];
}

__global__ __launch_bounds__(256) void scan_out_kernel(const int* __restrict__ cnt,
        const int* __restrict__ boff, int* __restrict__ row_ptr,
        int* __restrict__ row_cur, int n) {
    __shared__ int stage[SCAN_BLK];
    __shared__ int part[256];
    int base = blockIdx.x * SCAN_BLK;
    int t = threadIdx.x;
    for (int i = t; i < SCAN_BLK; i += 256) {
        int idx = base + i;
        stage[i] = (idx < n) ? cnt[idx] : 0;
    }
    __syncthreads();
    int loc = 0;
#pragma unroll
    for (int j = 0; j < 16; ++j) loc += stage[t * 16 + j];
    part[t] = loc;
    __syncthreads();
    for (int off = 1; off < 256; off <<= 1) {
        int v = (t >= off) ? part[t - off] : 0;
        __syncthreads();
        part[t] += v;
        __syncthreads();
    }
    int run = boff[blockIdx.x] + ((t == 0) ? 0 : part[t - 1]);
#pragma unroll
    for (int j = 0; j < 16; ++j) {
        int idx = base + t * 16 + j;
        if (idx < n) {
            row_ptr[idx] = run;
            row_cur[idx] = run;
        }
        run += stage[t * 16 + j];
    }
}

__global__ void scatter_kernel(const int* __restrict__ src, const int* __restrict__ dst,
        const int* __restrict__ et, int* __restrict__ row_cur, int* __restrict__ eperm,
        int E, int N) {
    int e = blockIdx.x * blockDim.x + threadIdx.x;
    if (e < E) {
        int r = et[e];
        if (r < 4) {
            int pos = atomicAdd(&row_cur[r * N + src[e]], 1);
            eperm[pos] = dst[e];
        }
    }
}

// ------------------------------ casts / weight prep ------------------------------

__global__ void cast_x_kernel(const float* __restrict__ x, u16* __restrict__ xb, int n4) {
    int i = blockIdx.x * blockDim.x + threadIdx.x;
    if (i < n4) {
        float4 v = reinterpret_cast<const float4*>(x)[i];
        ushort4 o;
        o.x = f2bf(v.x); o.y = f2bf(v.y); o.z = f2bf(v.z); o.w = f2bf(v.w);
        reinterpret_cast<ushort4*>(xb)[i] = o;
    }
}

// Wcat[ci][n][k] bf16 (n<256 -> rel_W[ci][ci][k][n] ; n>=256 -> root_W[ci][k][n-256])
__global__ void build_wt_kernel(const float* __restrict__ rel_W,
                                const float* __restrict__ root_W, u16* __restrict__ Wcat) {
    int t = blockIdx.x * blockDim.x + threadIdx.x;   // 4*512*256 total
    int k = t & 255;
    int n = (t >> 8) & 511;
    int ci = t >> 17;
    float v;
    if (n < 256) v = rel_W[(((size_t)ci * 5 + ci) * 256 + k) * 256 + n];
    else         v = root_W[((size_t)ci * 256 + k) * 256 + (n - 256)];
    Wcat[t] = f2bf(v);
}

// fc1t[n][k] = fc1_w[k][n], bf16. n<256, k<512.
__global__ void build_fc1t_kernel(const float* __restrict__ fc1_w, u16* __restrict__ fc1t) {
    int t = blockIdx.x * blockDim.x + threadIdx.x;   // 256*512 total
    int k = t & 511;
    int n = t >> 9;
    fc1t[t] = f2bf(fc1_w[(size_t)k * 256 + n]);
}

// ------------------------------ bf16 MFMA GEMM ------------------------------
// A [M,K] bf16 row-major; Bt [NN,K] bf16 row-major (pre-transposed weights).
// Tile: BM=64 (4 waves x 16 rows), BN=128, BK=64. B staged in LDS with 3-bit XOR
// swizzle (source-side pre-swizzle for global_load_lds + swizzled ds_read).
// MODE 0 (conv): gn<256 -> out_bf=hr (bf16, no bias); gn>=256 -> out_f=root (fp32 +bias)
// MODE 1 (fc1):  out_bf = relu(acc + bias) bf16, row stride ldo_bf.

#define BM 64
#define BN 128
#define BK 64

template <int MODE>
__global__ __launch_bounds__(256) void gemm_mfma(
        const u16* __restrict__ A, const u16* __restrict__ Bt, int M, int K,
        u16* __restrict__ out_bf, float* __restrict__ out_f,
        const float* __restrict__ bias, int ldo_bf) {
    __shared__ u16 Bs[BN * BK];   // 16 KB, physically swizzled

    const int tid  = threadIdx.x;
    const int wave = tid >> 6, lane = tid & 63;
    const int l15 = lane & 15, lg = lane >> 4;
    const int m0 = blockIdx.x * BM + wave * 16;
    const int n0 = blockIdx.y * BN;

    f32x4 acc[8];
#pragma unroll
    for (int j = 0; j < 8; ++j) acc[j] = (f32x4){0.f, 0.f, 0.f, 0.f};

    const int  arow = m0 + l15;
    const bool aval = arow < M;
    const u16* Arow = A + (size_t)arow * K;

    for (int k0 = 0; k0 < K; k0 += BK) {
        __syncthreads();
        // stage B tile: 16 KB = 4 issues x 256 lanes x 16 B. LDS dest linear
        // (tid*16); source global address carries the inverse swizzle.
#pragma unroll
        for (int i = 0; i < 4; ++i) {
            int phys = i * 4096 + tid * 16;
            int n    = phys >> 7;                       // row within tile (128 B rows)
            int cl   = (phys & 127) ^ ((n & 7) << 4);   // logical byte within row
            const u16* srcp = Bt + (size_t)(n0 + n) * K + k0 + (cl >> 1);
            __builtin_amdgcn_global_load_lds(
                (const __attribute__((address_space(1))) void*)srcp,
                (__attribute__((address_space(3))) void*)((char*)Bs + phys), 16, 0, 0);
        }
        bf16x8 afr[2];
        if (aval) {
            afr[0] = *reinterpret_cast<const bf16x8*>(Arow + k0 + lg * 8);
            afr[1] = *reinterpret_cast<const bf16x8*>(Arow + k0 + 32 + lg * 8);
        } else {
            afr[0] = afr[1] = (bf16x8){0, 0, 0, 0, 0, 0, 0, 0};
        }
        __syncthreads();   // drains vmcnt(0) -> staged tile + A frags ready
#pragma unroll
        for (int kk = 0; kk < 2; ++kk) {
#pragma unroll
            for (int j = 0; j < 8; ++j) {
                int n    = j * 16 + l15;
                int cl   = kk * 64 + lg * 16;
                int phys = n * 128 + (cl ^ ((n & 7) << 4));
                bf16x8 bfr = *reinterpret_cast<const bf16x8*>((const char*)Bs + phys);
                acc[j] = __builtin_amdgcn_mfma_f32_16x16x32_bf16(afr[kk], bfr, acc[j], 0, 0, 0);
            }
        }
    }

    // epilogue: D col = lane&15, row = (lane>>4)*4 + reg  [m89/m91 verified]
    const int orow = m0 + lg * 4;
#pragma unroll
    for (int j = 0; j < 8; ++j) {
        int gn = n0 + j * 16 + l15;
#pragma unroll
        for (int r = 0; r < 4; ++r) {
            int m = orow + r;
            if (m >= M) continue;
            float v = acc[j][r];
            if (MODE == 0) {
                if (gn < 256) out_bf[(size_t)m * 256 + gn] = f2bf(v);
                else          out_f[(size_t)m * 256 + gn - 256] = v + bias[gn - 256];
            } else {
                v = fmaxf(v + bias[gn], 0.0f);
                out_bf[(size_t)m * ldo_bf + gn] = f2bf(v);
            }
        }
    }
}

// ------------------------------ edge aggregation (bf16) ------------------------------
// dst[node, coff + :] = relu(mean_{edges}(hr[dst_node]) + root[node]) as bf16.
// One wave per node; row_ptr pre-offset by ci*N (per-rel CSR).

__global__ __launch_bounds__(256) void aggregate_kernel(const u16* __restrict__ hr,
        const int* __restrict__ row_ptr, const int* __restrict__ eperm,
        const float* __restrict__ root, u16* __restrict__ dst,
        int ldo, int coff, int N) {
    int node = blockIdx.x * 4 + (threadIdx.x >> 6);
    int lane = threadIdx.x & 63;
    if (node >= N) return;

    int beg = row_ptr[node];
    int end = row_ptr[node + 1];
    float a0 = 0.f, a1 = 0.f, a2 = 0.f, a3 = 0.f;
    for (int e = beg; e < end; ++e) {
        int d = eperm[e];
        ushort4 v = *reinterpret_cast<const ushort4*>(hr + (size_t)d * 256 + lane * 4);
        a0 += bf2f(v.x); a1 += bf2f(v.y); a2 += bf2f(v.z); a3 += bf2f(v.w);
    }
    float inv = 1.0f / fmaxf((float)(end - beg), 1.0f);
    float4 r = *reinterpret_cast<const float4*>(root + (size_t)node * 256 + lane * 4);
    ushort4 o;
    o.x = f2bf(fmaxf(fmaf(a0, inv, r.x), 0.0f));
    o.y = f2bf(fmaxf(fmaf(a1, inv, r.y), 0.0f));
    o.z = f2bf(fmaxf(fmaf(a2, inv, r.z), 0.0f));
    o.w = f2bf(fmaxf(fmaf(a3, inv, r.w), 0.0f));
    *reinterpret_cast<ushort4*>(dst + (size_t)node * ldo + coff + lane * 4) = o;
}

// ------------------------------ fc2 + log_softmax head ------------------------------

__global__ __launch_bounds__(256) void head_kernel(const u16* __restrict__ hid,
        const float* __restrict__ w2, const float* __restrict__ b2,
        float* __restrict__ out, int N) {
    int node = blockIdx.x * 4 + (threadIdx.x >> 6);
    int lane = threadIdx.x & 63;
    if (node >= N) return;

    ushort4 h4 = *reinterpret_cast<const ushort4*>(hid + (size_t)node * 256 + lane * 4);
    const float hv[4] = {bf2f(h4.x), bf2f(h4.y), bf2f(h4.z), bf2f(h4.w)};

    float acc[16];
#pragma unroll
    for (int o = 0; o < 16; ++o) acc[o] = 0.0f;
#pragma unroll
    for (int j = 0; j < 4; ++j) {
        int k = lane * 4 + j;
        const float4 w0 = *reinterpret_cast<const float4*>(w2 + (size_t)k * 16 + 0);
        const float4 w1 = *reinterpret_cast<const float4*>(w2 + (size_t)k * 16 + 4);
        const float4 w2v = *reinterpret_cast<const float4*>(w2 + (size_t)k * 16 + 8);
        const float4 w3 = *reinterpret_cast<const float4*>(w2 + (size_t)k * 16 + 12);
        acc[0] = fmaf(hv[j], w0.x, acc[0]);   acc[1] = fmaf(hv[j], w0.y, acc[1]);
        acc[2] = fmaf(hv[j], w0.z, acc[2]);   acc[3] = fmaf(hv[j], w0.w, acc[3]);
        acc[4] = fmaf(hv[j], w1.x, acc[4]);   acc[5] = fmaf(hv[j], w1.y, acc[5]);
        acc[6] = fmaf(hv[j], w1.z, acc[6]);   acc[7] = fmaf(hv[j], w1.w, acc[7]);
        acc[8] = fmaf(hv[j], w2v.x, acc[8]);  acc[9] = fmaf(hv[j], w2v.y, acc[9]);
        acc[10] = fmaf(hv[j], w2v.z, acc[10]); acc[11] = fmaf(hv[j], w2v.w, acc[11]);
        acc[12] = fmaf(hv[j], w3.x, acc[12]); acc[13] = fmaf(hv[j], w3.y, acc[13]);
        acc[14] = fmaf(hv[j], w3.z, acc[14]); acc[15] = fmaf(hv[j], w3.w, acc[15]);
    }
#pragma unroll
    for (int o = 0; o < 16; ++o) {
        float v = acc[o];
#pragma unroll
        for (int s = 32; s >= 1; s >>= 1) v += __shfl_xor(v, s);
        acc[o] = v + b2[o];
    }
    float mx = acc[0];
#pragma unroll
    for (int o = 1; o < 16; ++o) mx = fmaxf(mx, acc[o]);
    float se = 0.0f;
#pragma unroll
    for (int o = 0; o < 16; ++o) se += expf(acc[o] - mx);
    float lse = mx + logf(se);
    if (lane < 16) out[(size_t)node * 16 + lane] = acc[lane] - lse;
}

// ------------------------------ launch ------------------------------

extern "C" void kernel_launch(void* const* d_in, const int* in_sizes, int n_in,
                              void* d_out, int out_size, void* d_ws, size_t ws_size,
                              hipStream_t stream) {
    const float* x      = (const float*)d_in[0];
    const int*   ei     = (const int*)d_in[1];
    const int*   et     = (const int*)d_in[2];
    const float* rel_W  = (const float*)d_in[3];
    const float* root_W = (const float*)d_in[4];
    const float* bias   = (const float*)d_in[5];
    const float* fc1_w  = (const float*)d_in[6];
    const float* fc1_b  = (const float*)d_in[7];
    const float* fc2_w  = (const float*)d_in[8];
    const float* fc2_b  = (const float*)d_in[9];
    float* out = (float*)d_out;

    const int N = in_sizes[0] / D;   // 20000
    const int E = in_sizes[2];       // 500000
    const int* src = ei;
    const int* dst = ei + E;

    char* w = (char*)d_ws;
    u16* xb    = (u16*)w;  w += (size_t)N * 256 * 2;
    u16* h1b   = (u16*)w;  w += (size_t)N * 256 * 2;
    u16* hcatb = (u16*)w;  w += (size_t)N * 512 * 2;
    u16* hr    = (u16*)w;  w += (size_t)N * 256 * 2;
    float* root = (float*)w; w += (size_t)N * 256 * 4;
    u16* Wcat  = (u16*)w;  w += (size_t)4 * 512 * 256 * 2;
    u16* fc1t  = (u16*)w;  w += (size_t)256 * 512 * 2;
    int* cnt     = (int*)w;  w += (size_t)4 * N * 4;
    int* row_ptr = (int*)w;  w += ((size_t)4 * N + 1) * 4;
    int* row_cur = (int*)w;  w += (size_t)4 * N * 4;
    int* eperm   = (int*)w;  w += (size_t)E * 4;
    int* bsum    = (int*)w;  w += 256 * 4;
    int* boff    = (int*)w;  w += 256 * 4;
    u16* hid = h1b;   // reuse after convs

    const int n_keys = 4 * N;
    const int nb = (n_keys + SCAN_BLK - 1) / SCAN_BLK;   // 20 for N=20000

    // per-relation CSR
    hipMemsetAsync(cnt, 0, (size_t)n_keys * 4, stream);
    hist_kernel<<<dim3((E + 255) / 256), dim3(256), 0, stream>>>(src, et, cnt, E, N);
    scan_reduce_kernel<<<dim3(nb), dim3(256), 0, stream>>>(cnt, bsum, n_keys);
    scan_sums_kernel<<<dim3(1), dim3(256), 0, stream>>>(bsum, boff, nb, row_ptr, n_keys);
    scan_out_kernel<<<dim3(nb), dim3(256), 0, stream>>>(cnt, boff, row_ptr, row_cur, n_keys);
    scatter_kernel<<<dim3((E + 255) / 256), dim3(256), 0, stream>>>(src, dst, et, row_cur, eperm, E, N);

    // precision prep
    cast_x_kernel<<<dim3((N * 256 / 4 + 255) / 256), dim3(256), 0, stream>>>(x, xb, N * 256 / 4);
    build_wt_kernel<<<dim3(4 * 512 * 256 / 256), dim3(256), 0, stream>>>(rel_W, root_W, Wcat);
    build_fc1t_kernel<<<dim3(256 * 512 / 256), dim3(256), 0, stream>>>(fc1_w, fc1t);

    dim3 gblock(256);
    dim3 ngrid((N + 3) / 4);
    dim3 cgrid((N + BM - 1) / BM, 512 / BN);   // conv fused NN=512
    dim3 fgrid((N + BM - 1) / BM, 256 / BN);   // fc1 NN=256

    for (int ci = 0; ci < 4; ++ci) {
        int mp = ci >> 1, hop = ci & 1;
        const u16* hin = (hop == 0) ? xb : h1b;
        gemm_mfma<0><<<cgrid, gblock, 0, stream>>>(hin, Wcat + (size_t)ci * 512 * 256,
                N, 256, hr, root, bias + (size_t)ci * 256, 256);
        u16* dstb; int ldo, coff;
        if (hop == 0) { dstb = h1b;   ldo = 256; coff = 0; }
        else          { dstb = hcatb; ldo = 512; coff = mp * 256; }
        aggregate_kernel<<<ngrid, gblock, 0, stream>>>(hr, row_ptr + (size_t)ci * N, eperm,
                root, dstb, ldo, coff, N);
    }
    // hid = relu(hcat @ fc1 + b)
    gemm_mfma<1><<<fgrid, gblock, 0, stream>>>(hcatb, fc1t, N, 512, hid, nullptr, fc1_b, 256);
    // out = log_softmax(hid @ fc2 + b)
    head_kernel<<<ngrid, gblock, 0, stream>>>(hid, fc2_w, fc2_b, out, N);
}

// Round 7
// 322.526 us; speedup vs baseline: 2.4378x; 1.0927x over previous
//
#include <hip/hip_runtime.h>
#include <hip/hip_bf16.h>

#define D 256
typedef unsigned short u16;
typedef __attribute__((ext_vector_type(8))) short bf16x8;
typedef __attribute__((ext_vector_type(4))) float f32x4;

__device__ inline u16 f2bf(float f) {
    unsigned u = __builtin_bit_cast(unsigned, f);
    unsigned r = (u + 0x7fff + ((u >> 16) & 1)) >> 16;   // RNE
    return (u16)r;
}
__device__ inline float bf2f(u16 u) {
    return __builtin_bit_cast(float, (unsigned)u << 16);
}

// ------------------------------ per-relation CSR build ------------------------------
// key = rel*N + src for rel in [0,4); rel 4 edges dropped (never aggregated).

__global__ void hist_kernel(const int* __restrict__ src, const int* __restrict__ et,
                            int* __restrict__ cnt, int E, int N) {
    int e = blockIdx.x * blockDim.x + threadIdx.x;
    if (e < E) {
        int r = et[e];
        if (r < 4) atomicAdd(&cnt[r * N + src[e]], 1);
    }
}

// ---- 3-phase device scan ----
#define SCAN_BLK 4096

__global__ __launch_bounds__(256) void scan_reduce_kernel(const int* __restrict__ cnt,
        int* __restrict__ bsum, int n) {
    __shared__ int s[256];
    int base = blockIdx.x * SCAN_BLK;
    int t = threadIdx.x;
    int sum = 0;
    for (int i = t; i < SCAN_BLK; i += 256) {
        int idx = base + i;
        if (idx < n) sum += cnt[idx];
    }
    s[t] = sum;
    __syncthreads();
    for (int off = 128; off > 0; off >>= 1) {
        if (t < off) s[t] += s[t + off];
        __syncthreads();
    }
    if (t == 0) bsum[blockIdx.x] = s[0];
}

__global__ __launch_bounds__(256) void scan_sums_kernel(const int* __restrict__ bsum,
        int* __restrict__ boff, int nb, int* __restrict__ row_ptr, int n) {
    __shared__ int s[256];
    int t = threadIdx.x;
    s[t] = (t < nb) ? bsum[t] : 0;
    __syncthreads();
    for (int off = 1; off < 256; off <<= 1) {
        int v = (t >= off) ? s[t - off] : 0;
        __syncthreads();
        s[t] += v;
        __syncthreads();
    }
    if (t < nb) boff[t] = (t == 0) ? 0 : s[t - 1];
    if (t == 255) row_ptr[n] = s[255];
}

__global__ __launch_bounds__(256) void scan_out_kernel(const int* __restrict__ cnt,
        const int* __restrict__ boff, int* __restrict__ row_ptr,
        int* __restrict__ row_cur, int n) {
    __shared__ int stage[SCAN_BLK];
    __shared__ int part[256];
    int base = blockIdx.x * SCAN_BLK;
    int t = threadIdx.x;
    for (int i = t; i < SCAN_BLK; i += 256) {
        int idx = base + i;
        stage[i] = (idx < n) ? cnt[idx] : 0;
    }
    __syncthreads();
    int loc = 0;
#pragma unroll
    for (int j = 0; j < 16; ++j) loc += stage[t * 16 + j];
    part[t] = loc;
    __syncthreads();
    for (int off = 1; off < 256; off <<= 1) {
        int v = (t >= off) ? part[t - off] : 0;
        __syncthreads();
        part[t] += v;
        __syncthreads();
    }
    int run = boff[blockIdx.x] + ((t == 0) ? 0 : part[t - 1]);
#pragma unroll
    for (int j = 0; j < 16; ++j) {
        int idx = base + t * 16 + j;
        if (idx < n) {
            row_ptr[idx] = run;
            row_cur[idx] = run;
        }
        run += stage[t * 16 + j];
    }
}

__global__ void scatter_kernel(const int* __restrict__ src, const int* __restrict__ dst,
        const int* __restrict__ et, int* __restrict__ row_cur, int* __restrict__ eperm,
        int E, int N) {
    int e = blockIdx.x * blockDim.x + threadIdx.x;
    if (e < E) {
        int r = et[e];
        if (r < 4) {
            int pos = atomicAdd(&row_cur[r * N + src[e]], 1);
            eperm[pos] = dst[e];
        }
    }
}

// ------------------------------ casts / weight prep ------------------------------

__global__ void cast_x_kernel(const float* __restrict__ x, u16* __restrict__ xb, int n4) {
    int i = blockIdx.x * blockDim.x + threadIdx.x;
    if (i < n4) {
        float4 v = reinterpret_cast<const float4*>(x)[i];
        ushort4 o;
        o.x = f2bf(v.x); o.y = f2bf(v.y); o.z = f2bf(v.z); o.w = f2bf(v.w);
        reinterpret_cast<ushort4*>(xb)[i] = o;
    }
}

// Wcat[ci][n][k] bf16 (n<256 -> rel_W[ci][ci][k][n] ; n>=256 -> root_W[ci][k][n-256])
__global__ void build_wt_kernel(const float* __restrict__ rel_W,
                                const float* __restrict__ root_W, u16* __restrict__ Wcat) {
    int t = blockIdx.x * blockDim.x + threadIdx.x;   // 4*512*256 total
    int k = t & 255;
    int n = (t >> 8) & 511;
    int ci = t >> 17;
    float v;
    if (n < 256) v = rel_W[(((size_t)ci * 5 + ci) * 256 + k) * 256 + n];
    else         v = root_W[((size_t)ci * 256 + k) * 256 + (n - 256)];
    Wcat[t] = f2bf(v);
}

// fc1t[n][k] = fc1_w[k][n], bf16. n<256, k<512.
__global__ void build_fc1t_kernel(const float* __restrict__ fc1_w, u16* __restrict__ fc1t) {
    int t = blockIdx.x * blockDim.x + threadIdx.x;   // 256*512 total
    int k = t & 511;
    int n = t >> 9;
    fc1t[t] = f2bf(fc1_w[(size_t)k * 256 + n]);
}

// fc2t[col][k] = fc2_w[k][col], bf16. col<16, k<256.
__global__ void build_fc2t_kernel(const float* __restrict__ fc2_w, u16* __restrict__ fc2t) {
    int t = blockIdx.x * blockDim.x + threadIdx.x;   // 4096 total
    int k = t & 255;
    int col = t >> 8;
    fc2t[t] = f2bf(fc2_w[(size_t)k * 16 + col]);
}

// ------------------------------ bf16 MFMA GEMM ------------------------------
// A [M,K] bf16 row-major; Bt [NN,K] bf16 row-major (pre-transposed weights).
// Tile: BM=64 (4 waves x 16 rows), BN=128, BK=64. B staged in LDS with 3-bit XOR
// swizzle (source-side pre-swizzle for global_load_lds + swizzled ds_read).
// MODE 0 (conv): gn<256 -> out_bf=hr (bf16); gn>=256 -> out_root (bf16, +bias)
// MODE 1 (fc1):  out_bf = relu(acc + bias) bf16, row stride ldo_bf.

#define BM 64
#define BN 128
#define BK 64

template <int MODE>
__global__ __launch_bounds__(256) void gemm_mfma(
        const u16* __restrict__ A, const u16* __restrict__ Bt, int M, int K,
        u16* __restrict__ out_bf, u16* __restrict__ out_root,
        const float* __restrict__ bias, int ldo_bf) {
    __shared__ u16 Bs[BN * BK];   // 16 KB, physically swizzled

    const int tid  = threadIdx.x;
    const int wave = tid >> 6, lane = tid & 63;
    const int l15 = lane & 15, lg = lane >> 4;
    const int m0 = blockIdx.x * BM + wave * 16;
    const int n0 = blockIdx.y * BN;

    f32x4 acc[8];
#pragma unroll
    for (int j = 0; j < 8; ++j) acc[j] = (f32x4){0.f, 0.f, 0.f, 0.f};

    const int  arow = m0 + l15;
    const bool aval = arow < M;
    const u16* Arow = A + (size_t)arow * K;

    for (int k0 = 0; k0 < K; k0 += BK) {
        __syncthreads();
#pragma unroll
        for (int i = 0; i < 4; ++i) {
            int phys = i * 4096 + tid * 16;
            int n    = phys >> 7;                       // row within tile (128 B rows)
            int cl   = (phys & 127) ^ ((n & 7) << 4);   // logical byte within row
            const u16* srcp = Bt + (size_t)(n0 + n) * K + k0 + (cl >> 1);
            __builtin_amdgcn_global_load_lds(
                (const __attribute__((address_space(1))) void*)srcp,
                (__attribute__((address_space(3))) void*)((char*)Bs + phys), 16, 0, 0);
        }
        bf16x8 afr[2];
        if (aval) {
            afr[0] = *reinterpret_cast<const bf16x8*>(Arow + k0 + lg * 8);
            afr[1] = *reinterpret_cast<const bf16x8*>(Arow + k0 + 32 + lg * 8);
        } else {
            afr[0] = afr[1] = (bf16x8){0, 0, 0, 0, 0, 0, 0, 0};
        }
        __syncthreads();   // drains vmcnt(0) -> staged tile ready
#pragma unroll
        for (int kk = 0; kk < 2; ++kk) {
#pragma unroll
            for (int j = 0; j < 8; ++j) {
                int n    = j * 16 + l15;
                int cl   = kk * 64 + lg * 16;
                int phys = n * 128 + (cl ^ ((n & 7) << 4));
                bf16x8 bfr = *reinterpret_cast<const bf16x8*>((const char*)Bs + phys);
                acc[j] = __builtin_amdgcn_mfma_f32_16x16x32_bf16(afr[kk], bfr, acc[j], 0, 0, 0);
            }
        }
    }

    // epilogue: D col = lane&15, row = (lane>>4)*4 + reg  [m89/m91 verified]
    const int orow = m0 + lg * 4;
#pragma unroll
    for (int j = 0; j < 8; ++j) {
        int gn = n0 + j * 16 + l15;
#pragma unroll
        for (int r = 0; r < 4; ++r) {
            int m = orow + r;
            if (m >= M) continue;
            float v = acc[j][r];
            if (MODE == 0) {
                if (gn < 256) out_bf[(size_t)m * 256 + gn] = f2bf(v);
                else          out_root[(size_t)m * 256 + gn - 256] = f2bf(v + bias[gn - 256]);
            } else {
                v = fmaxf(v + bias[gn], 0.0f);
                out_bf[(size_t)m * ldo_bf + gn] = f2bf(v);
            }
        }
    }
}

// ------------------------------ edge aggregation (bf16) ------------------------------
// dst[node, coff + :] = relu(mean_{edges}(hr[dst_node]) + root[node]) as bf16.
// One wave per node; row_ptr pre-offset by ci*N (per-rel CSR).

__global__ __launch_bounds__(256) void aggregate_kernel(const u16* __restrict__ hr,
        const int* __restrict__ row_ptr, const int* __restrict__ eperm,
        const u16* __restrict__ rootb, u16* __restrict__ dst,
        int ldo, int coff, int N) {
    int node = blockIdx.x * 4 + (threadIdx.x >> 6);
    int lane = threadIdx.x & 63;
    if (node >= N) return;

    int beg = row_ptr[node];
    int end = row_ptr[node + 1];
    float a0 = 0.f, a1 = 0.f, a2 = 0.f, a3 = 0.f;
    for (int e = beg; e < end; ++e) {
        int d = eperm[e];
        ushort4 v = *reinterpret_cast<const ushort4*>(hr + (size_t)d * 256 + lane * 4);
        a0 += bf2f(v.x); a1 += bf2f(v.y); a2 += bf2f(v.z); a3 += bf2f(v.w);
    }
    float inv = 1.0f / fmaxf((float)(end - beg), 1.0f);
    ushort4 r4 = *reinterpret_cast<const ushort4*>(rootb + (size_t)node * 256 + lane * 4);
    ushort4 o;
    o.x = f2bf(fmaxf(fmaf(a0, inv, bf2f(r4.x)), 0.0f));
    o.y = f2bf(fmaxf(fmaf(a1, inv, bf2f(r4.y)), 0.0f));
    o.z = f2bf(fmaxf(fmaf(a2, inv, bf2f(r4.z)), 0.0f));
    o.w = f2bf(fmaxf(fmaf(a3, inv, bf2f(r4.w)), 0.0f));
    *reinterpret_cast<ushort4*>(dst + (size_t)node * ldo + coff + lane * 4) = o;
}

// ------------------------------ fc2 + log_softmax head (MFMA) ------------------------------
// One wave handles 16 nodes: [16,256]x[256,16] via 8 chained mfma_16x16x32.
// D layout: col=lane&15, row=(lane>>4)*4+r. Softmax over cols = 16-lane-group
// shfl_xor reduce (masks 1,2,4,8). 2 shuffles/node vs 96 in the old head.

__global__ __launch_bounds__(256) void head_mfma_kernel(const u16* __restrict__ hid,
        const u16* __restrict__ w2t, const float* __restrict__ b2,
        float* __restrict__ out, int N) {
    int tile = blockIdx.x * 4 + (threadIdx.x >> 6);   // 16 nodes per tile
    int lane = threadIdx.x & 63;
    int l15 = lane & 15, lg = lane >> 4;
    int ntiles = (N + 15) / 16;
    if (tile >= ntiles) return;

    int anode = tile * 16 + l15;
    if (anode >= N) anode = N - 1;                    // clamp (dup compute, guarded store)
    const u16* Arow = hid + (size_t)anode * 256;
    const u16* Brow = w2t + (size_t)l15 * 256;        // col = l15

    f32x4 acc = (f32x4){0.f, 0.f, 0.f, 0.f};
#pragma unroll
    for (int k0 = 0; k0 < 256; k0 += 32) {
        bf16x8 a = *reinterpret_cast<const bf16x8*>(Arow + k0 + lg * 8);
        bf16x8 b = *reinterpret_cast<const bf16x8*>(Brow + k0 + lg * 8);
        acc = __builtin_amdgcn_mfma_f32_16x16x32_bf16(a, b, acc, 0, 0, 0);
    }
    float bcol = b2[l15];
#pragma unroll
    for (int r = 0; r < 4; ++r) {
        float v = acc[r] + bcol;
        float mx = v;
        mx = fmaxf(mx, __shfl_xor(mx, 1));
        mx = fmaxf(mx, __shfl_xor(mx, 2));
        mx = fmaxf(mx, __shfl_xor(mx, 4));
        mx = fmaxf(mx, __shfl_xor(mx, 8));
        float e = expf(v - mx);
        float s = e;
        s += __shfl_xor(s, 1);
        s += __shfl_xor(s, 2);
        s += __shfl_xor(s, 4);
        s += __shfl_xor(s, 8);
        float lse = mx + logf(s);
        int row = tile * 16 + lg * 4 + r;
        if (row < N) out[(size_t)row * 16 + l15] = v - lse;
    }
}

// ------------------------------ launch ------------------------------

extern "C" void kernel_launch(void* const* d_in, const int* in_sizes, int n_in,
                              void* d_out, int out_size, void* d_ws, size_t ws_size,
                              hipStream_t stream) {
    const float* x      = (const float*)d_in[0];
    const int*   ei     = (const int*)d_in[1];
    const int*   et     = (const int*)d_in[2];
    const float* rel_W  = (const float*)d_in[3];
    const float* root_W = (const float*)d_in[4];
    const float* bias   = (const float*)d_in[5];
    const float* fc1_w  = (const float*)d_in[6];
    const float* fc1_b  = (const float*)d_in[7];
    const float* fc2_w  = (const float*)d_in[8];
    const float* fc2_b  = (const float*)d_in[9];
    float* out = (float*)d_out;

    const int N = in_sizes[0] / D;   // 20000
    const int E = in_sizes[2];       // 500000
    const int* src = ei;
    const int* dst = ei + E;

    char* w = (char*)d_ws;
    u16* xb    = (u16*)w;  w += (size_t)N * 256 * 2;
    u16* h1b   = (u16*)w;  w += (size_t)N * 256 * 2;
    u16* hcatb = (u16*)w;  w += (size_t)N * 512 * 2;
    u16* hr    = (u16*)w;  w += (size_t)N * 256 * 2;
    u16* rootb = (u16*)w;  w += (size_t)N * 256 * 2;
    u16* Wcat  = (u16*)w;  w += (size_t)4 * 512 * 256 * 2;
    u16* fc1t  = (u16*)w;  w += (size_t)256 * 512 * 2;
    u16* fc2t  = (u16*)w;  w += (size_t)16 * 256 * 2;
    int* cnt     = (int*)w;  w += (size_t)4 * N * 4;
    int* row_ptr = (int*)w;  w += ((size_t)4 * N + 1) * 4;
    int* row_cur = (int*)w;  w += (size_t)4 * N * 4;
    int* eperm   = (int*)w;  w += (size_t)E * 4;
    int* bsum    = (int*)w;  w += 256 * 4;
    int* boff    = (int*)w;  w += 256 * 4;
    u16* hid = h1b;   // reuse after convs

    const int n_keys = 4 * N;
    const int nb = (n_keys + SCAN_BLK - 1) / SCAN_BLK;   // 20 for N=20000

    // per-relation CSR
    hipMemsetAsync(cnt, 0, (size_t)n_keys * 4, stream);
    hist_kernel<<<dim3((E + 255) / 256), dim3(256), 0, stream>>>(src, et, cnt, E, N);
    scan_reduce_kernel<<<dim3(nb), dim3(256), 0, stream>>>(cnt, bsum, n_keys);
    scan_sums_kernel<<<dim3(1), dim3(256), 0, stream>>>(bsum, boff, nb, row_ptr, n_keys);
    scan_out_kernel<<<dim3(nb), dim3(256), 0, stream>>>(cnt, boff, row_ptr, row_cur, n_keys);
    scatter_kernel<<<dim3((E + 255) / 256), dim3(256), 0, stream>>>(src, dst, et, row_cur, eperm, E, N);

    // precision prep
    cast_x_kernel<<<dim3((N * 256 / 4 + 255) / 256), dim3(256), 0, stream>>>(x, xb, N * 256 / 4);
    build_wt_kernel<<<dim3(4 * 512 * 256 / 256), dim3(256), 0, stream>>>(rel_W, root_W, Wcat);
    build_fc1t_kernel<<<dim3(256 * 512 / 256), dim3(256), 0, stream>>>(fc1_w, fc1t);
    build_fc2t_kernel<<<dim3(16), dim3(256), 0, stream>>>(fc2_w, fc2t);

    dim3 gblock(256);
    dim3 ngrid((N + 3) / 4);
    dim3 cgrid((N + BM - 1) / BM, 512 / BN);   // conv fused NN=512
    dim3 fgrid((N + BM - 1) / BM, 256 / BN);   // fc1 NN=256

    for (int ci = 0; ci < 4; ++ci) {
        int mp = ci >> 1, hop = ci & 1;
        const u16* hin = (hop == 0) ? xb : h1b;
        gemm_mfma<0><<<cgrid, gblock, 0, stream>>>(hin, Wcat + (size_t)ci * 512 * 256,
                N, 256, hr, rootb, bias + (size_t)ci * 256, 256);
        u16* dstb; int ldo, coff;
        if (hop == 0) { dstb = h1b;   ldo = 256; coff = 0; }
        else          { dstb = hcatb; ldo = 512; coff = mp * 256; }
        aggregate_kernel<<<ngrid, gblock, 0, stream>>>(hr, row_ptr + (size_t)ci * N, eperm,
                rootb, dstb, ldo, coff, N);
    }
    // hid = relu(hcat @ fc1 + b)
    gemm_mfma<1><<<fgrid, gblock, 0, stream>>>(hcatb, fc1t, N, 512, hid, nullptr, fc1_b, 256);
    // out = log_softmax(hid @ fc2 + b)
    int ntiles = (N + 15) / 16;
    head_mfma_kernel<<<dim3((ntiles + 3) / 4), gblock, 0, stream>>>(hid, fc2t, fc2_b, out, N);
}

// Round 9
// 301.218 us; speedup vs baseline: 2.6102x; 1.0707x over previous
//
#include <hip/hip_runtime.h>
#include <hip/hip_bf16.h>

#define D 256
typedef unsigned short u16;
typedef __attribute__((ext_vector_type(8))) short bf16x8;
typedef __attribute__((ext_vector_type(4))) float f32x4;

__device__ inline u16 f2bf(float f) {
    unsigned u = __builtin_bit_cast(unsigned, f);
    unsigned r = (u + 0x7fff + ((u >> 16) & 1)) >> 16;   // RNE
    return (u16)r;
}
__device__ inline float bf2f(u16 u) {
    return __builtin_bit_cast(float, (unsigned)u << 16);
}

// ------------------------------ per-relation CSR build ------------------------------
// key = rel*N + src for rel in [0,4); rel 4 edges dropped (never aggregated).

__global__ void hist_kernel(const int* __restrict__ src, const int* __restrict__ et,
                            int* __restrict__ cnt, int E, int N) {
    int e = blockIdx.x * blockDim.x + threadIdx.x;
    if (e < E) {
        int r = et[e];
        if (r < 4) atomicAdd(&cnt[r * N + src[e]], 1);
    }
}

#define SCAN_BLK 4096

__global__ __launch_bounds__(256) void scan_reduce_kernel(const int* __restrict__ cnt,
        int* __restrict__ bsum, int n) {
    __shared__ int s[256];
    int base = blockIdx.x * SCAN_BLK;
    int t = threadIdx.x;
    int sum = 0;
    for (int i = t; i < SCAN_BLK; i += 256) {
        int idx = base + i;
        if (idx < n) sum += cnt[idx];
    }
    s[t] = sum;
    __syncthreads();
    for (int off = 128; off > 0; off >>= 1) {
        if (t < off) s[t] += s[t + off];
        __syncthreads();
    }
    if (t == 0) bsum[blockIdx.x] = s[0];
}

__global__ __launch_bounds__(256) void scan_sums_kernel(const int* __restrict__ bsum,
        int* __restrict__ boff, int nb, int* __restrict__ row_ptr, int n) {
    __shared__ int s[256];
    int t = threadIdx.x;
    s[t] = (t < nb) ? bsum[t] : 0;
    __syncthreads();
    for (int off = 1; off < 256; off <<= 1) {
        int v = (t >= off) ? s[t - off] : 0;
        __syncthreads();
        s[t] += v;
        __syncthreads();
    }
    if (t < nb) boff[t] = (t == 0) ? 0 : s[t - 1];
    if (t == 255) row_ptr[n] = s[255];
}

__global__ __launch_bounds__(256) void scan_out_kernel(const int* __restrict__ cnt,
        const int* __restrict__ boff, int* __restrict__ row_ptr,
        int* __restrict__ row_cur, int n) {
    __shared__ int stage[SCAN_BLK];
    __shared__ int part[256];
    int base = blockIdx.x * SCAN_BLK;
    int t = threadIdx.x;
    for (int i = t; i < SCAN_BLK; i += 256) {
        int idx = base + i;
        stage[i] = (idx < n) ? cnt[idx] : 0;
    }
    __syncthreads();
    int loc = 0;
#pragma unroll
    for (int j = 0; j < 16; ++j) loc += stage[t * 16 + j];
    part[t] = loc;
    __syncthreads();
    for (int off = 1; off < 256; off <<= 1) {
        int v = (t >= off) ? part[t - off] : 0;
        __syncthreads();
        part[t] += v;
        __syncthreads();
    }
    int run = boff[blockIdx.x] + ((t == 0) ? 0 : part[t - 1]);
#pragma unroll
    for (int j = 0; j < 16; ++j) {
        int idx = base + t * 16 + j;
        if (idx < n) {
            row_ptr[idx] = run;
            row_cur[idx] = run;
        }
        run += stage[t * 16 + j];
    }
}

__global__ void scatter_kernel(const int* __restrict__ src, const int* __restrict__ dst,
        const int* __restrict__ et, int* __restrict__ row_cur, int* __restrict__ eperm,
        int E, int N) {
    int e = blockIdx.x * blockDim.x + threadIdx.x;
    if (e < E) {
        int r = et[e];
        if (r < 4) {
            int pos = atomicAdd(&row_cur[r * N + src[e]], 1);
            eperm[pos] = dst[e];
        }
    }
}

// ------------------------------ fused prep ------------------------------
// 1) cast x -> bf16 (N*64 float4 items)
// 2) Bcat[5][256][512]: conv ci<4: Bt[n][k] = k<256 ? rel_W[ci][ci][k][n]
//    : root_W[ci][k-256][n]; ci==4: fc1_w[k][n]
// 3) fc2t[16][256]: fc2_w[k][col]

__global__ __launch_bounds__(256) void prep_kernel(const float* __restrict__ x,
        const float* __restrict__ rel_W, const float* __restrict__ root_W,
        const float* __restrict__ fc1_w, const float* __restrict__ fc2_w,
        u16* __restrict__ xb, u16* __restrict__ Bcat, u16* __restrict__ fc2t, int N) {
    int i = blockIdx.x * 256 + threadIdx.x;
    int nx = N * 64;                       // float4 count
    if (i < nx) {
        float4 v = reinterpret_cast<const float4*>(x)[i];
        ushort4 o;
        o.x = f2bf(v.x); o.y = f2bf(v.y); o.z = f2bf(v.z); o.w = f2bf(v.w);
        reinterpret_cast<ushort4*>(xb)[i] = o;
        return;
    }
    int j = i - nx;
    if (j < 5 * 131072) {
        int mi = j >> 17;                  // matrix 0..4
        int t = j & 131071;
        int k = t & 511;
        int n = t >> 9;                    // 0..255
        float v;
        if (mi < 4) {
            v = (k < 256) ? rel_W[(((size_t)mi * 5 + mi) * 256 + k) * 256 + n]
                          : root_W[((size_t)mi * 256 + (k - 256)) * 256 + n];
        } else {
            v = fc1_w[(size_t)k * 256 + n];
        }
        Bcat[(size_t)mi * 131072 + (size_t)n * 512 + k] = f2bf(v);
        return;
    }
    int h = j - 5 * 131072;
    if (h < 4096) {
        int k = h & 255;
        int col = h >> 8;
        fc2t[(size_t)col * 256 + k] = f2bf(fc2_w[(size_t)k * 16 + col]);
    }
}

// ------------------------------ mean aggregation (pure gather) ------------------------------
// out[node,:] = mean_{e in rp[node]..rp[node+1]} h[eperm[e],:]  (bf16 in/out, fp32 accum)
// One wave per node. gridDim.y==2 -> dual (rpA->outA, rpB->outB) from same h.

__global__ __launch_bounds__(256) void agg_kernel(const u16* __restrict__ h,
        const int* __restrict__ rpA, const int* __restrict__ rpB,
        const int* __restrict__ eperm,
        u16* __restrict__ outA, u16* __restrict__ outB, int N) {
    int node = blockIdx.x * 4 + (threadIdx.x >> 6);
    int lane = threadIdx.x & 63;
    if (node >= N) return;
    const int* rp = (blockIdx.y == 0) ? rpA : rpB;
    u16* outp     = (blockIdx.y == 0) ? outA : outB;

    int beg = rp[node];
    int end = rp[node + 1];
    float a0 = 0.f, a1 = 0.f, a2 = 0.f, a3 = 0.f;
    for (int e = beg; e < end; ++e) {
        int d = eperm[e];
        ushort4 v = *reinterpret_cast<const ushort4*>(h + (size_t)d * 256 + lane * 4);
        a0 += bf2f(v.x); a1 += bf2f(v.y); a2 += bf2f(v.z); a3 += bf2f(v.w);
    }
    float inv = 1.0f / fmaxf((float)(end - beg), 1.0f);
    ushort4 o;
    o.x = f2bf(a0 * inv);
    o.y = f2bf(a1 * inv);
    o.z = f2bf(a2 * inv);
    o.w = f2bf(a3 * inv);
    *reinterpret_cast<ushort4*>(outp + (size_t)node * 256 + lane * 4) = o;
}

// ------------------------------ bf16 MFMA GEMM (K=512, NN=256) ------------------------------
// out[m, coff+n] = relu( sum_k A[m,k]*Bt[n,k] + bias[n] ), A = [Alo | Ahi] split at k=256.
// Tile: BM=64 (4 waves x 16 rows), BN=128, BK=64, 8 K-steps. B staged via
// global_load_lds w=16 with 3-bit XOR swizzle (pre-swizzled source, swizzled read).

__global__ __launch_bounds__(256) void gemm512(
        const u16* __restrict__ Alo, int ldlo, const u16* __restrict__ Ahi, int ldhi,
        const u16* __restrict__ Bt, int M,
        u16* __restrict__ outp, int ldo, int coff, const float* __restrict__ bias) {
    __shared__ u16 Bs[128 * 64];   // 16 KB, physically swizzled

    const int tid  = threadIdx.x;
    const int wave = tid >> 6, lane = tid & 63;
    const int l15 = lane & 15, lg = lane >> 4;
    const int m0 = blockIdx.x * 64 + wave * 16;
    const int n0 = blockIdx.y * 128;

    f32x4 acc[8];
#pragma unroll
    for (int j = 0; j < 8; ++j) acc[j] = (f32x4){0.f, 0.f, 0.f, 0.f};

    const int  arow = m0 + l15;
    const bool aval = arow < M;

#pragma unroll
    for (int k0 = 0; k0 < 512; k0 += 64) {
        __syncthreads();
#pragma unroll
        for (int i = 0; i < 4; ++i) {
            int phys = i * 4096 + tid * 16;
            int n    = phys >> 7;                       // B-row within tile (128 B rows)
            int cl   = (phys & 127) ^ ((n & 7) << 4);   // logical byte within row
            const u16* srcp = Bt + (size_t)(n0 + n) * 512 + k0 + (cl >> 1);
            __builtin_amdgcn_global_load_lds(
                (const __attribute__((address_space(1))) void*)srcp,
                (__attribute__((address_space(3))) void*)((char*)Bs + phys), 16, 0, 0);
        }
        const u16* Ab = (k0 < 256) ? (Alo + (size_t)arow * ldlo + k0)
                                   : (Ahi + (size_t)arow * ldhi + (k0 - 256));
        bf16x8 afr0, afr1;
        if (aval) {
            afr0 = *reinterpret_cast<const bf16x8*>(Ab + lg * 8);
            afr1 = *reinterpret_cast<const bf16x8*>(Ab + 32 + lg * 8);
        } else {
            afr0 = afr1 = (bf16x8){0, 0, 0, 0, 0, 0, 0, 0};
        }
        __syncthreads();   // drains vmcnt(0) -> staged tile ready
#pragma unroll
        for (int kk = 0; kk < 2; ++kk) {
#pragma unroll
            for (int j = 0; j < 8; ++j) {
                int n    = j * 16 + l15;
                int cl   = kk * 64 + lg * 16;
                int phys = n * 128 + (cl ^ ((n & 7) << 4));
                bf16x8 bfr = *reinterpret_cast<const bf16x8*>((const char*)Bs + phys);
                acc[j] = __builtin_amdgcn_mfma_f32_16x16x32_bf16(kk ? afr1 : afr0, bfr, acc[j], 0, 0, 0);
            }
        }
    }

    // epilogue: D col = lane&15, row = (lane>>4)*4 + reg  [m89/m91 verified]
    const int orow = m0 + lg * 4;
#pragma unroll
    for (int j = 0; j < 8; ++j) {
        int gn = n0 + j * 16 + l15;
        float b = bias[gn];
#pragma unroll
        for (int r = 0; r < 4; ++r) {
            int m = orow + r;
            if (m >= M) continue;
            float v = fmaxf(acc[j][r] + b, 0.0f);
            outp[(size_t)m * ldo + coff + gn] = f2bf(v);
        }
    }
}

// ------------------------------ fc2 + log_softmax head (MFMA) ------------------------------

__global__ __launch_bounds__(256) void head_mfma_kernel(const u16* __restrict__ hid,
        const u16* __restrict__ w2t, const float* __restrict__ b2,
        float* __restrict__ out, int N) {
    int tile = blockIdx.x * 4 + (threadIdx.x >> 6);   // 16 nodes per tile
    int lane = threadIdx.x & 63;
    int l15 = lane & 15, lg = lane >> 4;
    int ntiles = (N + 15) / 16;
    if (tile >= ntiles) return;

    int anode = tile * 16 + l15;
    if (anode >= N) anode = N - 1;                    // clamp (dup compute, guarded store)
    const u16* Arow = hid + (size_t)anode * 256;
    const u16* Brow = w2t + (size_t)l15 * 256;        // col = l15

    f32x4 acc = (f32x4){0.f, 0.f, 0.f, 0.f};
#pragma unroll
    for (int k0 = 0; k0 < 256; k0 += 32) {
        bf16x8 a = *reinterpret_cast<const bf16x8*>(Arow + k0 + lg * 8);
        bf16x8 b = *reinterpret_cast<const bf16x8*>(Brow + k0 + lg * 8);
        acc = __builtin_amdgcn_mfma_f32_16x16x32_bf16(a, b, acc, 0, 0, 0);
    }
    float bcol = b2[l15];
#pragma unroll
    for (int r = 0; r < 4; ++r) {
        float v = acc[r] + bcol;
        float mx = v;
        mx = fmaxf(mx, __shfl_xor(mx, 1));
        mx = fmaxf(mx, __shfl_xor(mx, 2));
        mx = fmaxf(mx, __shfl_xor(mx, 4));
        mx = fmaxf(mx, __shfl_xor(mx, 8));
        float e = expf(v - mx);
        float s = e;
        s += __shfl_xor(s, 1);
        s += __shfl_xor(s, 2);
        s += __shfl_xor(s, 4);
        s += __shfl_xor(s, 8);
        float lse = mx + logf(s);
        int row = tile * 16 + lg * 4 + r;
        if (row < N) out[(size_t)row * 16 + l15] = v - lse;
    }
}

// ------------------------------ launch ------------------------------

extern "C" void kernel_launch(void* const* d_in, const int* in_sizes, int n_in,
                              void* d_out, int out_size, void* d_ws, size_t ws_size,
                              hipStream_t stream) {
    const float* x      = (const float*)d_in[0];
    const int*   ei     = (const int*)d_in[1];
    const int*   et     = (const int*)d_in[2];
    const float* rel_W  = (const float*)d_in[3];
    const float* root_W = (const float*)d_in[4];
    const float* bias   = (const float*)d_in[5];
    const float* fc1_w  = (const float*)d_in[6];
    const float* fc1_b  = (const float*)d_in[7];
    const float* fc2_w  = (const float*)d_in[8];
    const float* fc2_b  = (const float*)d_in[9];
    float* out = (float*)d_out;

    const int N = in_sizes[0] / D;   // 20000
    const int E = in_sizes[2];       // 500000
    const int* src = ei;
    const int* dst = ei + E;

    char* w = (char*)d_ws;
    u16* xb    = (u16*)w;  w += (size_t)N * 256 * 2;
    u16* h1b   = (u16*)w;  w += (size_t)N * 256 * 2;
    u16* hcatb = (u16*)w;  w += (size_t)N * 512 * 2;
    u16* aggA  = (u16*)w;  w += (size_t)N * 256 * 2;
    u16* aggB  = (u16*)w;  w += (size_t)N * 256 * 2;
    u16* Bcat  = (u16*)w;  w += (size_t)5 * 256 * 512 * 2;
    u16* fc2t  = (u16*)w;  w += (size_t)16 * 256 * 2;
    int* cnt     = (int*)w;  w += (size_t)4 * N * 4;
    int* row_ptr = (int*)w;  w += ((size_t)4 * N + 1) * 4;
    int* row_cur = (int*)w;  w += (size_t)4 * N * 4;
    int* eperm   = (int*)w;  w += (size_t)E * 4;
    int* bsum    = (int*)w;  w += 256 * 4;
    int* boff    = (int*)w;  w += 256 * 4;
    u16* hid = h1b;   // reuse after convs

    const int n_keys = 4 * N;
    const int nb = (n_keys + SCAN_BLK - 1) / SCAN_BLK;   // 20 for N=20000

    // per-relation CSR
    hipMemsetAsync(cnt, 0, (size_t)n_keys * 4, stream);
    hist_kernel<<<dim3((E + 255) / 256), dim3(256), 0, stream>>>(src, et, cnt, E, N);
    scan_reduce_kernel<<<dim3(nb), dim3(256), 0, stream>>>(cnt, bsum, n_keys);
    scan_sums_kernel<<<dim3(1), dim3(256), 0, stream>>>(bsum, boff, nb, row_ptr, n_keys);
    scan_out_kernel<<<dim3(nb), dim3(256), 0, stream>>>(cnt, boff, row_ptr, row_cur, n_keys);
    scatter_kernel<<<dim3((E + 255) / 256), dim3(256), 0, stream>>>(src, dst, et, row_cur, eperm, E, N);

    // fused prep
    {
        int total = N * 64 + 5 * 131072 + 4096;
        prep_kernel<<<dim3((total + 255) / 256), dim3(256), 0, stream>>>(
                x, rel_W, root_W, fc1_w, fc2_w, xb, Bcat, fc2t, N);
    }

    dim3 gblock(256);
    dim3 ngrid1((N + 3) / 4, 1);
    dim3 ngrid2((N + 3) / 4, 2);
    dim3 ggrid((N + 63) / 64, 2);    // BN=128, NN=256

    // hop-0 aggregations for both metapaths read only x -> fused dual launch
    agg_kernel<<<ngrid2, gblock, 0, stream>>>(xb, row_ptr, row_ptr + 2 * N, eperm, aggA, aggB, N);

    // mp0 hop0: h1 = relu([aggA|x] @ [W0;R0] + b0)
    gemm512<<<ggrid, gblock, 0, stream>>>(aggA, 256, xb, 256, Bcat + 0 * 131072, N,
                                          h1b, 256, 0, bias + 0 * 256);
    // mp0 hop1
    agg_kernel<<<ngrid1, gblock, 0, stream>>>(h1b, row_ptr + 1 * N, row_ptr + 1 * N, eperm, aggA, aggA, N);
    gemm512<<<ggrid, gblock, 0, stream>>>(aggA, 256, h1b, 256, Bcat + 1 * 131072, N,
                                          hcatb, 512, 0, bias + 1 * 256);
    // mp1 hop0: h1' = relu([aggB|x] @ [W2;R2] + b2)
    gemm512<<<ggrid, gblock, 0, stream>>>(aggB, 256, xb, 256, Bcat + 2 * 131072, N,
                                          h1b, 256, 0, bias + 2 * 256);
    // mp1 hop1
    agg_kernel<<<ngrid1, gblock, 0, stream>>>(h1b, row_ptr + 3 * N, row_ptr + 3 * N, eperm, aggA, aggA, N);
    gemm512<<<ggrid, gblock, 0, stream>>>(aggA, 256, h1b, 256, Bcat + 3 * 131072, N,
                                          hcatb, 512, 256, bias + 3 * 256);
    // fc1: hid = relu(hcat @ fc1 + b), A = hcat split halves
    gemm512<<<ggrid, gblock, 0, stream>>>(hcatb, 512, hcatb + 256, 512, Bcat + 4 * 131072, N,
                                          hid, 256, 0, fc1_b);
    // head
    int ntiles = (N + 15) / 16;
    head_mfma_kernel<<<dim3((ntiles + 3) / 4), gblock, 0, stream>>>(hid, fc2t, fc2_b, out, N);
}